// Round 4
// baseline (2897.798 us; speedup 1.0000x reference)
//
#include <hip/hip_runtime.h>
#include <hip/hip_bf16.h>
#include <math.h>
#include <stdint.h>

typedef unsigned short u16;
typedef __bf16 bf16x8 __attribute__((ext_vector_type(8)));
typedef float f32x4 __attribute__((ext_vector_type(4)));
typedef unsigned short u16x8 __attribute__((ext_vector_type(8)));
typedef unsigned short u16x4 __attribute__((ext_vector_type(4)));
typedef float f32x4v __attribute__((ext_vector_type(4)));

#define LOG2E 1.44269504088896340736f
#define S_LEN 4096
#define EMB 3072
#define NH 12
#define NKV 4
#define HD 256
#define KVDIM 1024

static __device__ __forceinline__ float b2f(u16 u) {
    union { unsigned int i; float f; } x; x.i = ((unsigned int)u) << 16; return x.f;
}
static __device__ __forceinline__ u16 f2b(float f) {
    union { float f; unsigned int i; } x; x.f = f;
    unsigned int r = (x.i + 0x7fffu + ((x.i >> 16) & 1u)) >> 16;
    return (u16)r;
}
static __device__ __forceinline__ f32x4 zero4() {
    f32x4 z; z[0] = 0.f; z[1] = 0.f; z[2] = 0.f; z[3] = 0.f; return z;
}
// async global->LDS, 16B per lane; LDS dest must be wave-uniform base + lane*16
static __device__ __forceinline__ void gld_lds16(const void* g, void* l) {
    __builtin_amdgcn_global_load_lds(
        (__attribute__((address_space(1))) void*)(uintptr_t)g,
        (__attribute__((address_space(3))) void*)l, 16, 0, 0);
}

// ---------------- fp32 -> bf16 elementwise convert (4/thread) ----------------
__global__ __launch_bounds__(256) void conv_f32_bf16(
    const float* __restrict__ in, u16* __restrict__ out, int n)
{
    int i = (blockIdx.x * 256 + threadIdx.x) * 4;
    if (i + 3 < n) {
        f32x4v v = *(const f32x4v*)(in + i);
        u16x4 o;
        o[0] = f2b(v[0]); o[1] = f2b(v[1]); o[2] = f2b(v[2]); o[3] = f2b(v[3]);
        *(u16x4*)(out + i) = o;
    } else {
        for (int j = i; j < n; ++j) out[j] = f2b(in[j]);
    }
}

// ---------------- fused convert+transpose: in[R][C] f32 -> out[C][R] bf16 ----------------
__global__ __launch_bounds__(256) void transpose_f32_bf16(
    const float* __restrict__ in, u16* __restrict__ out, int R, int C)
{
    __shared__ u16 t[64][65];
    const int tid = threadIdx.x;
    const int c0 = blockIdx.x * 64, r0 = blockIdx.y * 64;
#pragma unroll
    for (int i = 0; i < 16; ++i) {
        int lin = i * 256 + tid;
        int r = lin >> 6, c = lin & 63;
        t[r][c] = f2b(in[(size_t)(r0 + r) * C + c0 + c]);
    }
    __syncthreads();
#pragma unroll
    for (int i = 0; i < 16; ++i) {
        int lin = i * 256 + tid;
        int c = lin >> 6, r = lin & 63;
        out[(size_t)(c0 + c) * R + r0 + r] = t[r][c];
    }
}

// ---------------- rope sin/cos table: tab[s][0..127]=cos, [128..255]=sin ----------------
__global__ __launch_bounds__(128) void sincos_kernel(
    const int* __restrict__ pos, float* __restrict__ tab)
{
    int s = blockIdx.x, t = threadIdx.x;
    float p = (float)pos[s];
    double e = (double)t / 128.0;              // arange(0,256,2)/256
    float inv = (float)(1.0 / pow(1000042.0, e));
    float a = p * inv;                          // fp32 product, matches ref
    tab[(size_t)s * 256 + t]       = cosf(a);
    tab[(size_t)s * 256 + 128 + t] = sinf(a);
}

// ---------------- RoPE applied in-place to Q (scaled 1/16) and K (bf16 buffers) ----------------
__global__ __launch_bounds__(128) void rope_kernel(
    u16* __restrict__ Qb, u16* __restrict__ Kb, const float* __restrict__ tab)
{
    int s = blockIdx.x, hh = blockIdx.y, t = threadIdx.x;
    const float* cs = tab + (size_t)s * 256;
    float c = cs[t], sn = cs[128 + t];
    u16* row;
    float scale;
    if (hh < NH) { row = Qb + (size_t)s * EMB + hh * HD; scale = 0.0625f; }
    else         { row = Kb + (size_t)s * KVDIM + (size_t)(hh - NH) * HD; scale = 1.0f; }
    float a = b2f(row[t]), b = b2f(row[t + 128]);
    float oa = (a * c - b * sn) * scale;
    float ob = (b * c + a * sn) * scale;
    row[t] = f2b(oa); row[t + 128] = f2b(ob);
}

// ---------------- GEMM: C[M][N] = A[M][K] * BT[N][K]^T  (bf16 in, f32 acc) ----------------
// OutT = u16 (store bf16) or float (store fp32)
template <typename OutT>
__global__ __launch_bounds__(256) void gemm_bt(
    const u16* __restrict__ A, const u16* __restrict__ BT, OutT* __restrict__ C,
    int M, int N, int K)
{
    __shared__ __align__(16) u16 As[128 * 32];
    __shared__ __align__(16) u16 Bs[128 * 32];
    const int tid = threadIdx.x;
    const int lane = tid & 63, wid = tid >> 6;
    const int m0 = blockIdx.y * 128, n0 = blockIdx.x * 128;
    const int wm = (wid >> 1) * 64, wn = (wid & 1) * 64;
    const int g = lane >> 4, c16 = lane & 15;
    f32x4 acc[4][4];
#pragma unroll
    for (int i = 0; i < 4; ++i)
#pragma unroll
        for (int j = 0; j < 4; ++j) acc[i][j] = zero4();
    const int nk = K >> 5;
    const u16* Ab = A + (size_t)m0 * K;
    const u16* Bb = BT + (size_t)n0 * K;
    for (int kt = 0; kt < nk; ++kt) {
#pragma unroll
        for (int r2 = 0; r2 < 2; ++r2) {
            int chunk = r2 * 256 + tid;       // 0..511
            int row = chunk >> 2, c8 = chunk & 3;
            gld_lds16(Ab + (size_t)row * K + kt * 32 + c8 * 8, &As[chunk * 8]);
            gld_lds16(Bb + (size_t)row * K + kt * 32 + c8 * 8, &Bs[chunk * 8]);
        }
        __syncthreads();
        bf16x8 af[4], bfr[4];
#pragma unroll
        for (int i = 0; i < 4; ++i) {
            af[i]  = *(const bf16x8*)&As[(wm + i * 16 + c16) * 32 + g * 8];
            bfr[i] = *(const bf16x8*)&Bs[(wn + i * 16 + c16) * 32 + g * 8];
        }
#pragma unroll
        for (int i = 0; i < 4; ++i)
#pragma unroll
            for (int j = 0; j < 4; ++j)
                acc[i][j] = __builtin_amdgcn_mfma_f32_16x16x32_bf16(af[i], bfr[j], acc[i][j], 0, 0, 0);
        __syncthreads();
    }
#pragma unroll
    for (int i = 0; i < 4; ++i)
#pragma unroll
        for (int j = 0; j < 4; ++j)
#pragma unroll
            for (int r = 0; r < 4; ++r) {
                int row = m0 + wm + i * 16 + g * 4 + r;
                int col = n0 + wn + j * 16 + c16;
                if constexpr (sizeof(OutT) == 2)
                    C[(size_t)row * N + col] = f2b(acc[i][j][r]);
                else
                    C[(size_t)row * N + col] = acc[i][j][r];
            }
}

// ---------------- fused causal GQA flash attention ----------------
// Q: [S][3072] bf16 (pre-scaled by 1/16, RoPE'd) - also output buffer (in-place per block slice)
// K: [S][1024] bf16 (RoPE'd), V: [S][1024] bf16
__global__ __launch_bounds__(256) void attn_kernel(
    u16* __restrict__ Q, const u16* __restrict__ Kb, const u16* __restrict__ Vb,
    const int* __restrict__ am)
{
    __shared__ __align__(16) u16 Ks[32 * 256];      // XOR-swizzled rows (byte ^= (row&7)<<4)
    __shared__ __align__(16) u16 Vt[256 * 40];      // V transposed [d][kv], row stride 40
    __shared__ __align__(16) u16 Ps[4][16 * 40];    // per-wave P tile [q][kv], row stride 40
    const int tid = threadIdx.x;
    const int lane = tid & 63, wid = tid >> 6;
    const int qb = blockIdx.x, h = blockIdx.y;
    const int kvh = h / 3;
    const int g = lane >> 4, c16 = lane & 15;

    // Q fragments held in registers for the whole block
    bf16x8 qf[8];
    {
        const u16* Qbase = Q + (size_t)(qb * 64 + wid * 16 + c16) * EMB + h * HD + g * 8;
#pragma unroll
        for (int kc = 0; kc < 8; ++kc)
            qf[kc] = *(const bf16x8*)(Qbase + kc * 32);
    }
    f32x4 acc[16];
#pragma unroll
    for (int i = 0; i < 16; ++i) acc[i] = zero4();
    float mrow[4] = { -INFINITY, -INFINITY, -INFINITY, -INFINITY };
    float lrow[4] = { 0.f, 0.f, 0.f, 0.f };

    const int kv_end = qb * 64 + 64;
    for (int kv0 = 0; kv0 < kv_end; kv0 += 32) {
        // stage K via global_load_lds with pre-swizzled source (linear dest)
        {
            const u16* Kg = Kb + (size_t)kv0 * KVDIM + kvh * HD;
#pragma unroll
            for (int seg = 0; seg < 4; ++seg) {
                int chunk = seg * 256 + tid;   // 0..1023 (16B units)
                int row = chunk >> 5;          // kv local 0..31
                int ps = chunk & 31;           // physical 16B slot in row
                int ls = ps ^ (row & 7);       // logical slot (inverse swizzle)
                gld_lds16(Kg + (size_t)row * KVDIM + ls * 8, &Ks[chunk * 8]);
            }
        }
        // stage V transposed (reg-staged)
        {
            const u16* Vg = Vb + (size_t)kv0 * KVDIM + kvh * HD;
#pragma unroll
            for (int seg = 0; seg < 4; ++seg) {
                int chunk = seg * 256 + tid;
                int kv = chunk >> 5;
                int c8 = chunk & 31;
                u16x8 v = *(const u16x8*)(Vg + (size_t)kv * KVDIM + c8 * 8);
#pragma unroll
                for (int j = 0; j < 8; ++j) Vt[(c8 * 8 + j) * 40 + kv] = v[j];
            }
        }
        __syncthreads();

        // scores: S = Q . K^T   (Q pre-scaled by 1/16)
        f32x4 sc[2]; sc[0] = zero4(); sc[1] = zero4();
#pragma unroll
        for (int kc = 0; kc < 8; ++kc) {
#pragma unroll
            for (int c = 0; c < 2; ++c) {
                int row = c * 16 + c16;
                int lin = row * 512 + kc * 64 + g * 16;
                int phys = lin ^ ((row & 7) << 4);
                bf16x8 kf = *(const bf16x8*)((const char*)Ks + phys);
                sc[c] = __builtin_amdgcn_mfma_f32_16x16x32_bf16(qf[kc], kf, sc[c], 0, 0, 0);
            }
        }
        // mask + online softmax (rows live in 16-lane groups)
        const int q_glob = qb * 64 + wid * 16 + g * 4;
        const int kvg0 = kv0 + c16;
        const int am0 = am[kvg0];
        const int am1 = am[kvg0 + 16];
        float p0[4], p1[4], alpha[4];
#pragma unroll
        for (int r = 0; r < 4; ++r) {
            int qr = q_glob + r;
            float s0 = (kvg0 <= qr && am0 > 0) ? sc[0][r] : -INFINITY;
            float s1 = (kvg0 + 16 <= qr && am1 > 0) ? sc[1][r] : -INFINITY;
            float v = fmaxf(s0, s1);
            v = fmaxf(v, __shfl_xor(v, 1));
            v = fmaxf(v, __shfl_xor(v, 2));
            v = fmaxf(v, __shfl_xor(v, 4));
            v = fmaxf(v, __shfl_xor(v, 8));
            float mn = fmaxf(mrow[r], v);
            float a = exp2f((mrow[r] - mn) * LOG2E);
            mrow[r] = mn;
            float e0 = exp2f((s0 - mn) * LOG2E);
            float e1 = exp2f((s1 - mn) * LOG2E);
            float psum = e0 + e1;
            psum += __shfl_xor(psum, 1);
            psum += __shfl_xor(psum, 2);
            psum += __shfl_xor(psum, 4);
            psum += __shfl_xor(psum, 8);
            lrow[r] = lrow[r] * a + psum;
            alpha[r] = a;
            p0[r] = e0; p1[r] = e1;
        }
        // rescale accumulator
#pragma unroll
        for (int i = 0; i < 16; ++i) {
            acc[i][0] *= alpha[0]; acc[i][1] *= alpha[1];
            acc[i][2] *= alpha[2]; acc[i][3] *= alpha[3];
        }
        // P -> per-wave LDS tile (layout change for PV A-operand)
        {
            u16* Pw = &Ps[wid][0];
#pragma unroll
            for (int r = 0; r < 4; ++r) {
                int q = g * 4 + r;
                Pw[q * 40 + c16]      = f2b(p0[r]);
                Pw[q * 40 + 16 + c16] = f2b(p1[r]);
            }
        }
        // PV: acc += P . V
        {
            const bf16x8 pa = *(const bf16x8*)&Ps[wid][c16 * 40 + g * 8];
#pragma unroll
            for (int nf = 0; nf < 16; ++nf) {
                bf16x8 vf = *(const bf16x8*)&Vt[(nf * 16 + c16) * 40 + g * 8];
                acc[nf] = __builtin_amdgcn_mfma_f32_16x16x32_bf16(pa, vf, acc[nf], 0, 0, 0);
            }
        }
        __syncthreads();
    }
    // epilogue: normalize, write O over Q slice
    {
        float rl[4];
#pragma unroll
        for (int r = 0; r < 4; ++r) rl[r] = 1.0f / lrow[r];
        u16* Ob = Q + (size_t)(qb * 64 + wid * 16) * EMB + h * HD;
#pragma unroll
        for (int nf = 0; nf < 16; ++nf)
#pragma unroll
            for (int r = 0; r < 4; ++r)
                Ob[(size_t)(g * 4 + r) * EMB + nf * 16 + c16] = f2b(acc[nf][r] * rl[r]);
    }
}

extern "C" void kernel_launch(void* const* d_in, const int* in_sizes, int n_in,
                              void* d_out, int out_size, void* d_ws, size_t ws_size,
                              hipStream_t stream)
{
    const float* hs  = (const float*)d_in[0];
    const int* am    = (const int*)d_in[1];
    const int* pos   = (const int*)d_in[2];
    const float* Wq  = (const float*)d_in[3];
    const float* Wk  = (const float*)d_in[4];
    const float* Wv  = (const float*)d_in[5];
    const float* Wo  = (const float*)d_in[6];
    float* out = (float*)d_out;

    float* tab = (float*)d_ws;                                   // 4096*256 f32 = 4 MB
    u16* p = (u16*)((char*)d_ws + (size_t)S_LEN * 256 * 4);
    u16* WqT = p; p += (size_t)3072 * 3072;
    u16* WkT = p; p += (size_t)1024 * 3072;
    u16* WvT = p; p += (size_t)1024 * 3072;
    u16* WoT = p; p += (size_t)3072 * 3072;
    u16* hsb = p; p += (size_t)S_LEN * EMB;
    u16* Q   = p; p += (size_t)S_LEN * EMB;    // becomes O after attention
    u16* K   = p; p += (size_t)S_LEN * KVDIM;
    u16* V   = p; p += (size_t)S_LEN * KVDIM;

    conv_f32_bf16<<<(S_LEN * EMB) / 1024, 256, 0, stream>>>(hs, hsb, S_LEN * EMB);
    transpose_f32_bf16<<<dim3(48, 48), 256, 0, stream>>>(Wq, WqT, 3072, 3072);
    transpose_f32_bf16<<<dim3(16, 48), 256, 0, stream>>>(Wk, WkT, 3072, 1024);
    transpose_f32_bf16<<<dim3(16, 48), 256, 0, stream>>>(Wv, WvT, 3072, 1024);
    transpose_f32_bf16<<<dim3(48, 48), 256, 0, stream>>>(Wo, WoT, 3072, 3072);
    sincos_kernel<<<S_LEN, 128, 0, stream>>>(pos, tab);
    gemm_bt<u16><<<dim3(24, 32), 256, 0, stream>>>(hsb, WqT, Q, 4096, 3072, 3072);
    gemm_bt<u16><<<dim3(8, 32), 256, 0, stream>>>(hsb, WkT, K, 4096, 1024, 3072);
    gemm_bt<u16><<<dim3(8, 32), 256, 0, stream>>>(hsb, WvT, V, 4096, 1024, 3072);
    rope_kernel<<<dim3(S_LEN, NH + NKV), 128, 0, stream>>>(Q, K, tab);
    attn_kernel<<<dim3(S_LEN / 64, NH), 256, 0, stream>>>(Q, K, V, am);
    gemm_bt<float><<<dim3(24, 32), 256, 0, stream>>>(Q, WoT, out, 4096, 3072, 3072);
}

// Round 5
// 869.322 us; speedup vs baseline: 3.3334x; 3.3334x over previous
//
#include <hip/hip_runtime.h>
#include <hip/hip_bf16.h>
#include <math.h>
#include <stdint.h>

typedef unsigned short u16;
typedef __bf16 bf16x8 __attribute__((ext_vector_type(8)));
typedef float f32x4 __attribute__((ext_vector_type(4)));
typedef unsigned short u16x8 __attribute__((ext_vector_type(8)));
typedef unsigned short u16x4 __attribute__((ext_vector_type(4)));
typedef float f32x4v __attribute__((ext_vector_type(4)));

#define LOG2E 1.44269504088896340736f
#define S_LEN 4096
#define EMB 3072
#define NH 12
#define NKV 4
#define HD 256
#define KVDIM 1024

static __device__ __forceinline__ float b2f(u16 u) {
    union { unsigned int i; float f; } x; x.i = ((unsigned int)u) << 16; return x.f;
}
static __device__ __forceinline__ u16 f2b(float f) {
    union { float f; unsigned int i; } x; x.f = f;
    unsigned int r = (x.i + 0x7fffu + ((x.i >> 16) & 1u)) >> 16;
    return (u16)r;
}
static __device__ __forceinline__ f32x4 zero4() {
    f32x4 z; z[0] = 0.f; z[1] = 0.f; z[2] = 0.f; z[3] = 0.f; return z;
}
// async global->LDS, 16B per lane; LDS dest must be wave-uniform base + lane*16
static __device__ __forceinline__ void gld_lds16(const void* g, void* l) {
    __builtin_amdgcn_global_load_lds(
        (__attribute__((address_space(1))) void*)(uintptr_t)g,
        (__attribute__((address_space(3))) void*)l, 16, 0, 0);
}

// ---------------- fp32 -> bf16 elementwise convert (4/thread) ----------------
__global__ __launch_bounds__(256) void conv_f32_bf16(
    const float* __restrict__ in, u16* __restrict__ out, int n)
{
    int i = (blockIdx.x * 256 + threadIdx.x) * 4;
    if (i + 3 < n) {
        f32x4v v = *(const f32x4v*)(in + i);
        u16x4 o;
        o[0] = f2b(v[0]); o[1] = f2b(v[1]); o[2] = f2b(v[2]); o[3] = f2b(v[3]);
        *(u16x4*)(out + i) = o;
    } else {
        for (int j = i; j < n; ++j) out[j] = f2b(in[j]);
    }
}

// ---------------- fused convert+transpose: in[R][C] f32 -> out[C][R] bf16 ----------------
__global__ __launch_bounds__(256) void transpose_f32_bf16(
    const float* __restrict__ in, u16* __restrict__ out, int R, int C)
{
    __shared__ u16 t[64][65];
    const int tid = threadIdx.x;
    const int c0 = blockIdx.x * 64, r0 = blockIdx.y * 64;
#pragma unroll
    for (int i = 0; i < 16; ++i) {
        int lin = i * 256 + tid;
        int r = lin >> 6, c = lin & 63;
        t[r][c] = f2b(in[(size_t)(r0 + r) * C + c0 + c]);
    }
    __syncthreads();
#pragma unroll
    for (int i = 0; i < 16; ++i) {
        int lin = i * 256 + tid;
        int c = lin >> 6, r = lin & 63;
        out[(size_t)(c0 + c) * R + r0 + r] = t[r][c];
    }
}

// ---------------- bf16 transpose: in[R][C] -> out[C][R] ----------------
__global__ __launch_bounds__(256) void transpose_u16(
    const u16* __restrict__ in, u16* __restrict__ out, int R, int C)
{
    __shared__ u16 t[64][65];
    const int tid = threadIdx.x;
    const int c0 = blockIdx.x * 64, r0 = blockIdx.y * 64;
#pragma unroll
    for (int i = 0; i < 16; ++i) {
        int lin = i * 256 + tid;
        int r = lin >> 6, c = lin & 63;
        t[r][c] = in[(size_t)(r0 + r) * C + c0 + c];
    }
    __syncthreads();
#pragma unroll
    for (int i = 0; i < 16; ++i) {
        int lin = i * 256 + tid;
        int c = lin >> 6, r = lin & 63;
        out[(size_t)(c0 + c) * R + r0 + r] = t[r][c];
    }
}

// ---------------- rope sin/cos table: tab[s][0..127]=cos, [128..255]=sin ----------------
__global__ __launch_bounds__(128) void sincos_kernel(
    const int* __restrict__ pos, float* __restrict__ tab)
{
    int s = blockIdx.x, t = threadIdx.x;
    float p = (float)pos[s];
    double e = (double)t / 128.0;              // arange(0,256,2)/256
    float inv = (float)(1.0 / pow(1000042.0, e));
    float a = p * inv;                          // fp32 product, matches ref
    tab[(size_t)s * 256 + t]       = cosf(a);
    tab[(size_t)s * 256 + 128 + t] = sinf(a);
}

// ---------------- RoPE applied in-place to Q (scaled 1/16) and K (bf16 buffers) ----------------
__global__ __launch_bounds__(128) void rope_kernel(
    u16* __restrict__ Qb, u16* __restrict__ Kb, const float* __restrict__ tab)
{
    int s = blockIdx.x, hh = blockIdx.y, t = threadIdx.x;
    const float* cs = tab + (size_t)s * 256;
    float c = cs[t], sn = cs[128 + t];
    u16* row;
    float scale;
    if (hh < NH) { row = Qb + (size_t)s * EMB + hh * HD; scale = 0.0625f; }
    else         { row = Kb + (size_t)s * KVDIM + (size_t)(hh - NH) * HD; scale = 1.0f; }
    float a = b2f(row[t]), b = b2f(row[t + 128]);
    float oa = (a * c - b * sn) * scale;
    float ob = (b * c + a * sn) * scale;
    row[t] = f2b(oa); row[t + 128] = f2b(ob);
}

// ---------------- GEMM: C[M][N] = A[M][K] * BT[N][K]^T  (bf16 in, f32 acc) ----------------
// OutT = u16 (store bf16) or float (store fp32)
template <typename OutT>
__global__ __launch_bounds__(256) void gemm_bt(
    const u16* __restrict__ A, const u16* __restrict__ BT, OutT* __restrict__ C,
    int M, int N, int K)
{
    __shared__ __align__(16) u16 As[128 * 32];
    __shared__ __align__(16) u16 Bs[128 * 32];
    const int tid = threadIdx.x;
    const int lane = tid & 63, wid = tid >> 6;
    const int m0 = blockIdx.y * 128, n0 = blockIdx.x * 128;
    const int wm = (wid >> 1) * 64, wn = (wid & 1) * 64;
    const int g = lane >> 4, c16 = lane & 15;
    f32x4 acc[4][4];
#pragma unroll
    for (int i = 0; i < 4; ++i)
#pragma unroll
        for (int j = 0; j < 4; ++j) acc[i][j] = zero4();
    const int nk = K >> 5;
    const u16* Ab = A + (size_t)m0 * K;
    const u16* Bb = BT + (size_t)n0 * K;
    for (int kt = 0; kt < nk; ++kt) {
#pragma unroll
        for (int r2 = 0; r2 < 2; ++r2) {
            int chunk = r2 * 256 + tid;       // 0..511
            int row = chunk >> 2, c8 = chunk & 3;
            gld_lds16(Ab + (size_t)row * K + kt * 32 + c8 * 8, &As[chunk * 8]);
            gld_lds16(Bb + (size_t)row * K + kt * 32 + c8 * 8, &Bs[chunk * 8]);
        }
        __syncthreads();
        bf16x8 af[4], bfr[4];
#pragma unroll
        for (int i = 0; i < 4; ++i) {
            af[i]  = *(const bf16x8*)&As[(wm + i * 16 + c16) * 32 + g * 8];
            bfr[i] = *(const bf16x8*)&Bs[(wn + i * 16 + c16) * 32 + g * 8];
        }
#pragma unroll
        for (int i = 0; i < 4; ++i)
#pragma unroll
            for (int j = 0; j < 4; ++j)
                acc[i][j] = __builtin_amdgcn_mfma_f32_16x16x32_bf16(af[i], bfr[j], acc[i][j], 0, 0, 0);
        __syncthreads();
    }
#pragma unroll
    for (int i = 0; i < 4; ++i)
#pragma unroll
        for (int j = 0; j < 4; ++j)
#pragma unroll
            for (int r = 0; r < 4; ++r) {
                int row = m0 + wm + i * 16 + g * 4 + r;
                int col = n0 + wn + j * 16 + c16;
                if constexpr (sizeof(OutT) == 2)
                    C[(size_t)row * N + col] = f2b(acc[i][j][r]);
                else
                    C[(size_t)row * N + col] = acc[i][j][r];
            }
}

// ---------------- fused causal GQA flash attention ----------------
// Q: [S][3072] bf16 (pre-scaled by 1/16, RoPE'd) - also output buffer (in-place per block slice)
// K: [S][1024] bf16 (RoPE'd), VtG: [1024][4096] bf16 (V transposed)
__global__ __launch_bounds__(256) void attn_kernel(
    u16* __restrict__ Q, const u16* __restrict__ Kb, const u16* __restrict__ VtG,
    const int* __restrict__ am)
{
    __shared__ __align__(16) u16 Ks[32 * 256];      // XOR-swizzled rows (byte ^= (row&7)<<4)
    __shared__ __align__(16) u16 Vt[256 * 32];      // V^T tile [d][kv], linear, gld_lds staged
    __shared__ __align__(16) u16 Ps[4][16 * 40];    // per-wave P tile [q][kv], row stride 40
    const int tid = threadIdx.x;
    const int lane = tid & 63, wid = tid >> 6;
    // longest-first order: qb descending, heads interleaved
    const int bx = blockIdx.x;
    const int qb = (S_LEN / 64 - 1) - (bx / NH);
    const int h  = bx % NH;
    const int kvh = h / 3;
    const int g = lane >> 4, c16 = lane & 15;

    // Q fragments held in registers for the whole block
    bf16x8 qf[8];
    {
        const u16* Qbase = Q + (size_t)(qb * 64 + wid * 16 + c16) * EMB + h * HD + g * 8;
#pragma unroll
        for (int kc = 0; kc < 8; ++kc)
            qf[kc] = *(const bf16x8*)(Qbase + kc * 32);
    }
    f32x4 acc[16];
#pragma unroll
    for (int i = 0; i < 16; ++i) acc[i] = zero4();
    float mrow[4] = { -INFINITY, -INFINITY, -INFINITY, -INFINITY };
    float lrow[4] = { 0.f, 0.f, 0.f, 0.f };

    const int kv_end = qb * 64 + 64;
    for (int kv0 = 0; kv0 < kv_end; kv0 += 32) {
        // stage K via global_load_lds with pre-swizzled source (linear dest)
        {
            const u16* Kg = Kb + (size_t)kv0 * KVDIM + kvh * HD;
#pragma unroll
            for (int seg = 0; seg < 4; ++seg) {
                int chunk = seg * 256 + tid;   // 0..1023 (16B units)
                int row = chunk >> 5;          // kv local 0..31
                int ps = chunk & 31;           // physical 16B slot in row
                int ls = ps ^ (row & 7);       // logical slot (inverse swizzle)
                gld_lds16(Kg + (size_t)row * KVDIM + ls * 8, &Ks[chunk * 8]);
            }
        }
        // stage V^T tile [256 d][32 kv] via global_load_lds (linear, conflict-free)
        {
            const u16* Vg = VtG + (size_t)kvh * HD * S_LEN + kv0;
#pragma unroll
            for (int seg = 0; seg < 4; ++seg) {
                int chunk = seg * 256 + tid;   // 0..1023
                int d = chunk >> 2;            // 0..255
                int part = chunk & 3;          // 16B part within 64B row
                gld_lds16(Vg + (size_t)d * S_LEN + part * 8, &Vt[chunk * 8]);
            }
        }
        __syncthreads();

        // scores: S = Q . K^T   (Q pre-scaled by 1/16)
        f32x4 sc[2]; sc[0] = zero4(); sc[1] = zero4();
#pragma unroll
        for (int kc = 0; kc < 8; ++kc) {
#pragma unroll
            for (int c = 0; c < 2; ++c) {
                int row = c * 16 + c16;
                int lin = row * 512 + kc * 64 + g * 16;
                int phys = lin ^ ((row & 7) << 4);
                bf16x8 kf = *(const bf16x8*)((const char*)Ks + phys);
                sc[c] = __builtin_amdgcn_mfma_f32_16x16x32_bf16(qf[kc], kf, sc[c], 0, 0, 0);
            }
        }
        // mask + online softmax (rows live in 16-lane groups)
        const int q_glob = qb * 64 + wid * 16 + g * 4;
        const int kvg0 = kv0 + c16;
        const int am0 = am[kvg0];
        const int am1 = am[kvg0 + 16];
        float p0[4], p1[4], alpha[4];
#pragma unroll
        for (int r = 0; r < 4; ++r) {
            int qr = q_glob + r;
            float s0 = (kvg0 <= qr && am0 > 0) ? sc[0][r] : -INFINITY;
            float s1 = (kvg0 + 16 <= qr && am1 > 0) ? sc[1][r] : -INFINITY;
            float v = fmaxf(s0, s1);
            v = fmaxf(v, __shfl_xor(v, 1));
            v = fmaxf(v, __shfl_xor(v, 2));
            v = fmaxf(v, __shfl_xor(v, 4));
            v = fmaxf(v, __shfl_xor(v, 8));
            float mn = fmaxf(mrow[r], v);
            float a = exp2f((mrow[r] - mn) * LOG2E);
            mrow[r] = mn;
            float e0 = exp2f((s0 - mn) * LOG2E);
            float e1 = exp2f((s1 - mn) * LOG2E);
            float psum = e0 + e1;
            psum += __shfl_xor(psum, 1);
            psum += __shfl_xor(psum, 2);
            psum += __shfl_xor(psum, 4);
            psum += __shfl_xor(psum, 8);
            lrow[r] = lrow[r] * a + psum;
            alpha[r] = a;
            p0[r] = e0; p1[r] = e1;
        }
        // rescale accumulator
#pragma unroll
        for (int i = 0; i < 16; ++i) {
            acc[i][0] *= alpha[0]; acc[i][1] *= alpha[1];
            acc[i][2] *= alpha[2]; acc[i][3] *= alpha[3];
        }
        // P -> per-wave LDS tile (layout change for PV A-operand)
        {
            u16* Pw = &Ps[wid][0];
#pragma unroll
            for (int r = 0; r < 4; ++r) {
                int q = g * 4 + r;
                Pw[q * 40 + c16]      = f2b(p0[r]);
                Pw[q * 40 + 16 + c16] = f2b(p1[r]);
            }
        }
        // PV: acc += P . V
        {
            const bf16x8 pa = *(const bf16x8*)&Ps[wid][c16 * 40 + g * 8];
#pragma unroll
            for (int nf = 0; nf < 16; ++nf) {
                bf16x8 vf = *(const bf16x8*)&Vt[(nf * 16 + c16) * 32 + g * 8];
                acc[nf] = __builtin_amdgcn_mfma_f32_16x16x32_bf16(pa, vf, acc[nf], 0, 0, 0);
            }
        }
        __syncthreads();
    }
    // epilogue: normalize, write O over Q slice
    {
        float rl[4];
#pragma unroll
        for (int r = 0; r < 4; ++r) rl[r] = 1.0f / lrow[r];
        u16* Ob = Q + (size_t)(qb * 64 + wid * 16) * EMB + h * HD;
#pragma unroll
        for (int nf = 0; nf < 16; ++nf)
#pragma unroll
            for (int r = 0; r < 4; ++r)
                Ob[(size_t)(g * 4 + r) * EMB + nf * 16 + c16] = f2b(acc[nf][r] * rl[r]);
    }
}

extern "C" void kernel_launch(void* const* d_in, const int* in_sizes, int n_in,
                              void* d_out, int out_size, void* d_ws, size_t ws_size,
                              hipStream_t stream)
{
    const float* hs  = (const float*)d_in[0];
    const int* am    = (const int*)d_in[1];
    const int* pos   = (const int*)d_in[2];
    const float* Wq  = (const float*)d_in[3];
    const float* Wk  = (const float*)d_in[4];
    const float* Wv  = (const float*)d_in[5];
    const float* Wo  = (const float*)d_in[6];
    float* out = (float*)d_out;

    float* tab = (float*)d_ws;                                   // 4096*256 f32 = 4 MB
    u16* p = (u16*)((char*)d_ws + (size_t)S_LEN * 256 * 4);
    u16* WqT = p; p += (size_t)3072 * 3072;
    u16* WkT = p; p += (size_t)1024 * 3072;
    u16* WvT = p; p += (size_t)1024 * 3072;
    u16* WoT = p; p += (size_t)3072 * 3072;
    u16* hsb = p; p += (size_t)S_LEN * EMB;
    u16* Q   = p; p += (size_t)S_LEN * EMB;    // becomes O after attention
    u16* K   = p; p += (size_t)S_LEN * KVDIM;
    u16* V   = p; p += (size_t)S_LEN * KVDIM;
    u16* VtG = p; p += (size_t)KVDIM * S_LEN;  // V transposed [1024][4096]

    conv_f32_bf16<<<(S_LEN * EMB) / 1024, 256, 0, stream>>>(hs, hsb, S_LEN * EMB);
    transpose_f32_bf16<<<dim3(48, 48), 256, 0, stream>>>(Wq, WqT, 3072, 3072);
    transpose_f32_bf16<<<dim3(16, 48), 256, 0, stream>>>(Wk, WkT, 3072, 1024);
    transpose_f32_bf16<<<dim3(16, 48), 256, 0, stream>>>(Wv, WvT, 3072, 1024);
    transpose_f32_bf16<<<dim3(48, 48), 256, 0, stream>>>(Wo, WoT, 3072, 3072);
    sincos_kernel<<<S_LEN, 128, 0, stream>>>(pos, tab);
    gemm_bt<u16><<<dim3(24, 32), 256, 0, stream>>>(hsb, WqT, Q, 4096, 3072, 3072);
    gemm_bt<u16><<<dim3(8, 32), 256, 0, stream>>>(hsb, WkT, K, 4096, 1024, 3072);
    gemm_bt<u16><<<dim3(8, 32), 256, 0, stream>>>(hsb, WvT, V, 4096, 1024, 3072);
    rope_kernel<<<dim3(S_LEN, NH + NKV), 128, 0, stream>>>(Q, K, tab);
    transpose_u16<<<dim3(16, 64), 256, 0, stream>>>(V, VtG, S_LEN, KVDIM);
    attn_kernel<<<S_LEN / 64 * NH, 256, 0, stream>>>(Q, K, VtG, am);
    gemm_bt<float><<<dim3(24, 32), 256, 0, stream>>>(Q, WoT, out, 4096, 3072, 3072);
}

// Round 6
// 731.444 us; speedup vs baseline: 3.9618x; 1.1885x over previous
//
#include <hip/hip_runtime.h>
#include <hip/hip_bf16.h>
#include <math.h>
#include <stdint.h>

typedef unsigned short u16;
typedef __bf16 bf16x8 __attribute__((ext_vector_type(8)));
typedef float f32x4 __attribute__((ext_vector_type(4)));
typedef unsigned short u16x8 __attribute__((ext_vector_type(8)));
typedef unsigned short u16x4 __attribute__((ext_vector_type(4)));
typedef float f32x4v __attribute__((ext_vector_type(4)));

#define LOG2E 1.44269504088896340736f
#define S_LEN 4096
#define EMB 3072
#define NH 12
#define NKV 4
#define HD 256
#define KVDIM 1024

static __device__ __forceinline__ float b2f(u16 u) {
    union { unsigned int i; float f; } x; x.i = ((unsigned int)u) << 16; return x.f;
}
static __device__ __forceinline__ u16 f2b(float f) {
    union { float f; unsigned int i; } x; x.f = f;
    unsigned int r = (x.i + 0x7fffu + ((x.i >> 16) & 1u)) >> 16;
    return (u16)r;
}
static __device__ __forceinline__ f32x4 zero4() {
    f32x4 z; z[0] = 0.f; z[1] = 0.f; z[2] = 0.f; z[3] = 0.f; return z;
}
// async global->LDS, 16B per lane; LDS dest must be wave-uniform base + lane*16
static __device__ __forceinline__ void gld_lds16(const void* g, void* l) {
    __builtin_amdgcn_global_load_lds(
        (__attribute__((address_space(1))) void*)(uintptr_t)g,
        (__attribute__((address_space(3))) void*)l, 16, 0, 0);
}

// ---------------- fp32 -> bf16 elementwise convert (4/thread) ----------------
__global__ __launch_bounds__(256) void conv_f32_bf16(
    const float* __restrict__ in, u16* __restrict__ out, int n)
{
    int i = (blockIdx.x * 256 + threadIdx.x) * 4;
    if (i + 3 < n) {
        f32x4v v = *(const f32x4v*)(in + i);
        u16x4 o;
        o[0] = f2b(v[0]); o[1] = f2b(v[1]); o[2] = f2b(v[2]); o[3] = f2b(v[3]);
        *(u16x4*)(out + i) = o;
    } else {
        for (int j = i; j < n; ++j) out[j] = f2b(in[j]);
    }
}

// ---------------- fused convert+transpose: in[R][C] f32 -> out[C][R] bf16 ----------------
__global__ __launch_bounds__(256) void transpose_f32_bf16(
    const float* __restrict__ in, u16* __restrict__ out, int R, int C)
{
    __shared__ u16 t[64][65];
    const int tid = threadIdx.x;
    const int c0 = blockIdx.x * 64, r0 = blockIdx.y * 64;
#pragma unroll
    for (int i = 0; i < 16; ++i) {
        int lin = i * 256 + tid;
        int r = lin >> 6, c = lin & 63;
        t[r][c] = f2b(in[(size_t)(r0 + r) * C + c0 + c]);
    }
    __syncthreads();
#pragma unroll
    for (int i = 0; i < 16; ++i) {
        int lin = i * 256 + tid;
        int c = lin >> 6, r = lin & 63;
        out[(size_t)(c0 + c) * R + r0 + r] = t[r][c];
    }
}

// ---------------- bf16 transpose: in[R][C] -> out[C][R] ----------------
__global__ __launch_bounds__(256) void transpose_u16(
    const u16* __restrict__ in, u16* __restrict__ out, int R, int C)
{
    __shared__ u16 t[64][65];
    const int tid = threadIdx.x;
    const int c0 = blockIdx.x * 64, r0 = blockIdx.y * 64;
#pragma unroll
    for (int i = 0; i < 16; ++i) {
        int lin = i * 256 + tid;
        int r = lin >> 6, c = lin & 63;
        t[r][c] = in[(size_t)(r0 + r) * C + c0 + c];
    }
    __syncthreads();
#pragma unroll
    for (int i = 0; i < 16; ++i) {
        int lin = i * 256 + tid;
        int c = lin >> 6, r = lin & 63;
        out[(size_t)(c0 + c) * R + r0 + r] = t[r][c];
    }
}

// ---------------- inv_freq (done once; avoids 524K device double-pows) ----------------
__global__ __launch_bounds__(128) void invfreq_kernel(float* __restrict__ invf)
{
    int t = threadIdx.x;
    double e = (double)t / 128.0;              // arange(0,256,2)/256
    invf[t] = (float)(1.0 / pow(1000042.0, e));
}

// ---------------- rope sin/cos table: tab[s][0..127]=cos, [128..255]=sin ----------------
__global__ __launch_bounds__(128) void sincos_kernel(
    const int* __restrict__ pos, const float* __restrict__ invf, float* __restrict__ tab)
{
    int s = blockIdx.x, t = threadIdx.x;
    float a = (float)pos[s] * invf[t];          // fp32 product, matches ref
    tab[(size_t)s * 256 + t]       = cosf(a);
    tab[(size_t)s * 256 + 128 + t] = sinf(a);
}

// ---------------- RoPE applied in-place to Q (scaled 1/16) and K (bf16 buffers) ----------------
__global__ __launch_bounds__(128) void rope_kernel(
    u16* __restrict__ Qb, u16* __restrict__ Kb, const float* __restrict__ tab)
{
    int s = blockIdx.x, hh = blockIdx.y, t = threadIdx.x;
    const float* cs = tab + (size_t)s * 256;
    float c = cs[t], sn = cs[128 + t];
    u16* row;
    float scale;
    if (hh < NH) { row = Qb + (size_t)s * EMB + hh * HD; scale = 0.0625f; }
    else         { row = Kb + (size_t)s * KVDIM + (size_t)(hh - NH) * HD; scale = 1.0f; }
    float a = b2f(row[t]), b = b2f(row[t + 128]);
    float oa = (a * c - b * sn) * scale;
    float ob = (b * c + a * sn) * scale;
    row[t] = f2b(oa); row[t + 128] = f2b(ob);
}

// ---------------- shared GEMM mainloop: 128x128 tile, BK=64, swizzled LDS ----------------
// rule #21: gld_lds writes linearly; apply inverse swizzle on SOURCE, same swizzle on READ.
static __device__ __forceinline__ void gemm_mainloop(
    const u16* __restrict__ A, const u16* __restrict__ BT, int K,
    int m0, int n0, int tid, u16* As, u16* Bs, f32x4 (&acc)[4][4])
{
    const int lane = tid & 63, wid = tid >> 6;
    const int wm = (wid >> 1) * 64, wn = (wid & 1) * 64;
    const int g = lane >> 4, c16 = lane & 15;
    const u16* Ab = A + (size_t)m0 * K;
    const u16* Bb = BT + (size_t)n0 * K;
    const int nk = K >> 6;
    for (int kt = 0; kt < nk; ++kt) {
#pragma unroll
        for (int r4 = 0; r4 < 4; ++r4) {
            int chunk = r4 * 256 + tid;          // 0..1023 (16B units)
            int row = chunk >> 3, c8 = chunk & 7;
            int ls = c8 ^ (row & 7);             // inverse-swizzled source slot
            gld_lds16(Ab + (size_t)row * K + kt * 64 + ls * 8, &As[chunk * 8]);
            gld_lds16(Bb + (size_t)row * K + kt * 64 + ls * 8, &Bs[chunk * 8]);
        }
        __syncthreads();
#pragma unroll
        for (int kk = 0; kk < 2; ++kk) {
            bf16x8 af[4], bfr[4];
#pragma unroll
            for (int i = 0; i < 4; ++i) {
                int ra = wm + i * 16 + c16;
                int rb = wn + i * 16 + c16;
                af[i]  = *(const bf16x8*)&As[ra * 64 + (((kk << 2) + g) ^ (ra & 7)) * 8];
                bfr[i] = *(const bf16x8*)&Bs[rb * 64 + (((kk << 2) + g) ^ (rb & 7)) * 8];
            }
#pragma unroll
            for (int i = 0; i < 4; ++i)
#pragma unroll
                for (int j = 0; j < 4; ++j)
                    acc[i][j] = __builtin_amdgcn_mfma_f32_16x16x32_bf16(af[i], bfr[j], acc[i][j], 0, 0, 0);
        }
        __syncthreads();
    }
}

// ---------------- merged QKV projection: C[4096][5120] split to Q/K/V ----------------
__global__ __launch_bounds__(256) void gemm_qkv(
    const u16* __restrict__ A, const u16* __restrict__ BT,
    u16* __restrict__ Qo, u16* __restrict__ Ko, u16* __restrict__ Vo)
{
    __shared__ __align__(16) u16 As[128 * 64];
    __shared__ __align__(16) u16 Bs[128 * 64];
    const int tid = threadIdx.x;
    const int m0 = blockIdx.y * 128, n0 = blockIdx.x * 128;
    f32x4 acc[4][4];
#pragma unroll
    for (int i = 0; i < 4; ++i)
#pragma unroll
        for (int j = 0; j < 4; ++j) acc[i][j] = zero4();
    gemm_mainloop(A, BT, EMB, m0, n0, tid, As, Bs, acc);
    const int lane = tid & 63, wid = tid >> 6;
    const int wm = (wid >> 1) * 64, wn = (wid & 1) * 64;
    const int g = lane >> 4, c16 = lane & 15;
    u16* dst; int ncol, cb;
    if (n0 < 3072)      { dst = Qo; ncol = EMB;   cb = 0; }
    else if (n0 < 4096) { dst = Ko; ncol = KVDIM; cb = 3072; }
    else                { dst = Vo; ncol = KVDIM; cb = 4096; }
#pragma unroll
    for (int i = 0; i < 4; ++i)
#pragma unroll
        for (int j = 0; j < 4; ++j)
#pragma unroll
            for (int r = 0; r < 4; ++r) {
                int row = m0 + wm + i * 16 + g * 4 + r;
                int col = n0 + wn + j * 16 + c16 - cb;
                dst[(size_t)row * ncol + col] = f2b(acc[i][j][r]);
            }
}

// ---------------- generic GEMM (out-projection, fp32 store) ----------------
__global__ __launch_bounds__(256) void gemm_bt_f32(
    const u16* __restrict__ A, const u16* __restrict__ BT, float* __restrict__ C,
    int M, int N, int K)
{
    __shared__ __align__(16) u16 As[128 * 64];
    __shared__ __align__(16) u16 Bs[128 * 64];
    const int tid = threadIdx.x;
    const int m0 = blockIdx.y * 128, n0 = blockIdx.x * 128;
    f32x4 acc[4][4];
#pragma unroll
    for (int i = 0; i < 4; ++i)
#pragma unroll
        for (int j = 0; j < 4; ++j) acc[i][j] = zero4();
    gemm_mainloop(A, BT, K, m0, n0, tid, As, Bs, acc);
    const int lane = tid & 63, wid = tid >> 6;
    const int wm = (wid >> 1) * 64, wn = (wid & 1) * 64;
    const int g = lane >> 4, c16 = lane & 15;
#pragma unroll
    for (int i = 0; i < 4; ++i)
#pragma unroll
        for (int j = 0; j < 4; ++j)
#pragma unroll
            for (int r = 0; r < 4; ++r) {
                int row = m0 + wm + i * 16 + g * 4 + r;
                int col = n0 + wn + j * 16 + c16;
                C[(size_t)row * N + col] = acc[i][j][r];
            }
}

// ---------------- fused causal GQA flash attention ----------------
// Q: [S][3072] bf16 (pre-scaled by 1/16, RoPE'd) - also output buffer (in-place per block slice)
// K: [S][1024] bf16 (RoPE'd), VtG: [1024][4096] bf16 (V transposed)
__global__ __launch_bounds__(256) void attn_kernel(
    u16* __restrict__ Q, const u16* __restrict__ Kb, const u16* __restrict__ VtG,
    const int* __restrict__ am)
{
    __shared__ __align__(16) u16 Ks[32 * 256];      // XOR-swizzled rows (byte ^= (row&7)<<4)
    __shared__ __align__(16) u16 Vt[256 * 32];      // V^T tile [d][kv], slot-swizzled
    __shared__ __align__(16) u16 Ps[4][16 * 40];    // per-wave P tile [q][kv], row stride 40
    const int tid = threadIdx.x;
    const int lane = tid & 63, wid = tid >> 6;
    // longest-first order: qb descending, heads interleaved
    const int bx = blockIdx.x;
    const int qb = (S_LEN / 64 - 1) - (bx / NH);
    const int h  = bx % NH;
    const int kvh = h / 3;
    const int g = lane >> 4, c16 = lane & 15;

    // Q fragments held in registers for the whole block
    bf16x8 qf[8];
    {
        const u16* Qbase = Q + (size_t)(qb * 64 + wid * 16 + c16) * EMB + h * HD + g * 8;
#pragma unroll
        for (int kc = 0; kc < 8; ++kc)
            qf[kc] = *(const bf16x8*)(Qbase + kc * 32);
    }
    f32x4 acc[16];
#pragma unroll
    for (int i = 0; i < 16; ++i) acc[i] = zero4();
    float mrow[4] = { -INFINITY, -INFINITY, -INFINITY, -INFINITY };
    float lrow[4] = { 0.f, 0.f, 0.f, 0.f };     // per-lane PARTIAL sums (reduced in epilogue)

    const int kv_end = qb * 64 + 64;
    for (int kv0 = 0; kv0 < kv_end; kv0 += 32) {
        // stage K via global_load_lds with pre-swizzled source (linear dest)
        {
            const u16* Kg = Kb + (size_t)kv0 * KVDIM + kvh * HD;
#pragma unroll
            for (int seg = 0; seg < 4; ++seg) {
                int chunk = seg * 256 + tid;   // 0..1023 (16B units)
                int row = chunk >> 5;          // kv local 0..31
                int ps = chunk & 31;           // physical 16B slot in row
                int ls = ps ^ (row & 7);       // logical slot (inverse swizzle)
                gld_lds16(Kg + (size_t)row * KVDIM + ls * 8, &Ks[chunk * 8]);
            }
        }
        // stage V^T tile [256 d][32 kv] via global_load_lds (slot-swizzled for read)
        {
            const u16* Vg = VtG + (size_t)kvh * HD * S_LEN + kv0;
#pragma unroll
            for (int seg = 0; seg < 4; ++seg) {
                int chunk = seg * 256 + tid;   // 0..1023
                int d = chunk >> 2;            // 0..255
                int part = chunk & 3;          // physical 16B part within 64B row
                int lp = part ^ (d & 3);       // logical slot (inverse swizzle)
                gld_lds16(Vg + (size_t)d * S_LEN + lp * 8, &Vt[chunk * 8]);
            }
        }
        __syncthreads();

        // scores: S = Q . K^T   (Q pre-scaled by 1/16)
        f32x4 sc[2]; sc[0] = zero4(); sc[1] = zero4();
#pragma unroll
        for (int kc = 0; kc < 8; ++kc) {
#pragma unroll
            for (int c = 0; c < 2; ++c) {
                int row = c * 16 + c16;
                int lin = row * 512 + kc * 64 + g * 16;
                int phys = lin ^ ((row & 7) << 4);
                bf16x8 kf = *(const bf16x8*)((const char*)Ks + phys);
                sc[c] = __builtin_amdgcn_mfma_f32_16x16x32_bf16(qf[kc], kf, sc[c], 0, 0, 0);
            }
        }
        // mask + defer-max online softmax (NO per-tile shfl reduction on the fast path)
        const int q_glob = qb * 64 + wid * 16 + g * 4;
        const int kvg0 = kv0 + c16;
        const int am0 = am[kvg0];
        const int am1 = am[kvg0 + 16];
        float s0[4], s1[4], p0[4], p1[4];
        bool grow = false;
#pragma unroll
        for (int r = 0; r < 4; ++r) {
            int qr = q_glob + r;
            s0[r] = (am0 > 0 && kvg0 <= qr) ? sc[0][r] : -INFINITY;
            s1[r] = (am1 > 0 && kvg0 + 16 <= qr) ? sc[1][r] : -INFINITY;
            grow |= (fmaxf(s0[r], s1[r]) > mrow[r] + 8.0f);
        }
        if (__any(grow)) {
            float alpha[4];
#pragma unroll
            for (int r = 0; r < 4; ++r) {
                float v = fmaxf(s0[r], s1[r]);
                v = fmaxf(v, __shfl_xor(v, 1));
                v = fmaxf(v, __shfl_xor(v, 2));
                v = fmaxf(v, __shfl_xor(v, 4));
                v = fmaxf(v, __shfl_xor(v, 8));
                float mn = fmaxf(mrow[r], v);
                float a = exp2f((mrow[r] - mn) * LOG2E);
                mrow[r] = mn;
                lrow[r] *= a;
                alpha[r] = a;
            }
#pragma unroll
            for (int i = 0; i < 16; ++i) {
                acc[i][0] *= alpha[0]; acc[i][1] *= alpha[1];
                acc[i][2] *= alpha[2]; acc[i][3] *= alpha[3];
            }
        }
#pragma unroll
        for (int r = 0; r < 4; ++r) {
            float e0 = exp2f((s0[r] - mrow[r]) * LOG2E);   // bounded by e^8
            float e1 = exp2f((s1[r] - mrow[r]) * LOG2E);
            lrow[r] += e0 + e1;
            p0[r] = e0; p1[r] = e1;
        }
        // P -> per-wave LDS tile (layout change for PV A-operand)
        {
            u16* Pw = &Ps[wid][0];
#pragma unroll
            for (int r = 0; r < 4; ++r) {
                int q = g * 4 + r;
                Pw[q * 40 + c16]      = f2b(p0[r]);
                Pw[q * 40 + 16 + c16] = f2b(p1[r]);
            }
        }
        // PV: acc += P . V
        {
            const bf16x8 pa = *(const bf16x8*)&Ps[wid][c16 * 40 + g * 8];
#pragma unroll
            for (int nf = 0; nf < 16; ++nf) {
                int d = nf * 16 + c16;
                bf16x8 vf = *(const bf16x8*)&Vt[d * 32 + ((g ^ (d & 3)) * 8)];
                acc[nf] = __builtin_amdgcn_mfma_f32_16x16x32_bf16(pa, vf, acc[nf], 0, 0, 0);
            }
        }
        __syncthreads();
    }
    // epilogue: reduce row sums across the 16-lane group, normalize, write O over Q slice
    {
        float rl[4];
#pragma unroll
        for (int r = 0; r < 4; ++r) {
            float l = lrow[r];
            l += __shfl_xor(l, 1);
            l += __shfl_xor(l, 2);
            l += __shfl_xor(l, 4);
            l += __shfl_xor(l, 8);
            rl[r] = 1.0f / l;
        }
        u16* Ob = Q + (size_t)(qb * 64 + wid * 16) * EMB + h * HD;
#pragma unroll
        for (int nf = 0; nf < 16; ++nf)
#pragma unroll
            for (int r = 0; r < 4; ++r)
                Ob[(size_t)(g * 4 + r) * EMB + nf * 16 + c16] = f2b(acc[nf][r] * rl[r]);
    }
}

extern "C" void kernel_launch(void* const* d_in, const int* in_sizes, int n_in,
                              void* d_out, int out_size, void* d_ws, size_t ws_size,
                              hipStream_t stream)
{
    const float* hs  = (const float*)d_in[0];
    const int* am    = (const int*)d_in[1];
    const int* pos   = (const int*)d_in[2];
    const float* Wq  = (const float*)d_in[3];
    const float* Wk  = (const float*)d_in[4];
    const float* Wv  = (const float*)d_in[5];
    const float* Wo  = (const float*)d_in[6];
    float* out = (float*)d_out;

    float* tab  = (float*)d_ws;                                  // 4096*256 f32 = 4 MB
    float* invf = tab + (size_t)S_LEN * 256;                     // 128 f32
    u16* p = (u16*)((char*)d_ws + (size_t)S_LEN * 256 * 4 + 512);
    u16* WqT = p; p += (size_t)3072 * 3072;                      // rows 0..3071 of merged BT
    u16* WkT = p; p += (size_t)1024 * 3072;                      // rows 3072..4095
    u16* WvT = p; p += (size_t)1024 * 3072;                      // rows 4096..5119
    u16* WoT = p; p += (size_t)3072 * 3072;
    u16* hsb = p; p += (size_t)S_LEN * EMB;
    u16* Q   = p; p += (size_t)S_LEN * EMB;    // becomes O after attention
    u16* K   = p; p += (size_t)S_LEN * KVDIM;
    u16* V   = p; p += (size_t)S_LEN * KVDIM;
    u16* VtG = p; p += (size_t)KVDIM * S_LEN;  // V transposed [1024][4096]

    conv_f32_bf16<<<(S_LEN * EMB) / 1024, 256, 0, stream>>>(hs, hsb, S_LEN * EMB);
    transpose_f32_bf16<<<dim3(48, 48), 256, 0, stream>>>(Wq, WqT, 3072, 3072);
    transpose_f32_bf16<<<dim3(16, 48), 256, 0, stream>>>(Wk, WkT, 3072, 1024);
    transpose_f32_bf16<<<dim3(16, 48), 256, 0, stream>>>(Wv, WvT, 3072, 1024);
    transpose_f32_bf16<<<dim3(48, 48), 256, 0, stream>>>(Wo, WoT, 3072, 3072);
    invfreq_kernel<<<1, 128, 0, stream>>>(invf);
    sincos_kernel<<<S_LEN, 128, 0, stream>>>(pos, invf, tab);
    // merged QKV projection: BT rows = [WqT; WkT; WvT] contiguous = 5120 x 3072
    gemm_qkv<<<dim3(40, 32), 256, 0, stream>>>(hsb, WqT, Q, K, V);
    rope_kernel<<<dim3(S_LEN, NH + NKV), 128, 0, stream>>>(Q, K, tab);
    transpose_u16<<<dim3(16, 64), 256, 0, stream>>>(V, VtG, S_LEN, KVDIM);
    attn_kernel<<<S_LEN / 64 * NH, 256, 0, stream>>>(Q, K, VtG, am);
    gemm_bt_f32<<<dim3(24, 32), 256, 0, stream>>>(Q, WoT, out, 4096, 3072, 3072);
}